// Round 1
// baseline (424.733 us; speedup 1.0000x reference)
//
#include <hip/hip_runtime.h>

// EMD via Sinkhorn on 64 Hamming states, eps=0.1.
// K = exp(-C/eps) = tensor product of six 2x2 [[1,a],[a,1]], a = exp(-10)
//   => K-apply is 6 butterfly stages.
//
// v2 restructure: each batch element is split across a LANE PAIR (lane^1):
//   32 states per lane. Register state drops 192 -> 96 floats, so the whole
//   working set fits in <=128 arch VGPRs -> 4 waves/SIMD (v1 was 240 regs =
//   2 waves/SIMD with P,Q shuttled through AGPRs every div step).
//   - bits 0..4 of the butterfly: in-lane, packed v_pk_fma_f32 (unchanged)
//   - bit 5: cross-lane, W += a * partner(W) via DPP quad_perm:[1,0,3,2]
//     (update_dpp builtin so the compiler owns DPP hazards; mov_dpp can fold
//      into v_fmac_f32_dpp)
// Scale invariance (map is 1-homogeneous): iterate on raw p and q scaled by
// sum(p)/sum(q); the single surviving 1/sum(p) is applied in the epilogue.
// Divide steps: batched-inverse pair trick (one rcp per 2 states), packed:
//   c  = v_pk_mul(X, W.swapped)        ; {X.lo*wh, X.hi*wl}
//   W' = v_pk_mul(c, r broadcast-low)  ; r = rcp(wl*wh) in LOW half only
// EMD readout (w = K v_final, u = p/w):
//   emd = (a * sum_b u.X_b w) / ((1-a^2) * sum(p)) - 6a^2/(1-a^2)
// Op order matches v1 (stages ascending bit0..bit5, ascending neighbor sums,
// same pair-rcp) -- only the two prologue/epilogue sum associations differ.

namespace {

typedef float v2f __attribute__((ext_vector_type(2)));

constexpr int   NL    = 32;   // states per lane
constexpr int   NPL   = 16;   // register pairs per lane; pair k = {2k, 2k+1}
constexpr int   NBITS = 6;
constexpr int   ITERS = 50;

constexpr double Ad = 4.5399929762484854e-05;           // exp(-10)
constexpr float  A  = (float)Ad;
constexpr float  EMD_SCALE = (float)(Ad / (1.0 - Ad * Ad));
constexpr float  EMD_DIAG  = (float)(6.0 * Ad * Ad / (1.0 - Ad * Ad));

__device__ __forceinline__ float rcp(float x) { return __builtin_amdgcn_rcpf(x); }

// partner (lane^1) value via DPP quad_perm:[1,0,3,2]; compiler handles
// DPP read-after-VALU-write hazards for the intrinsic.
__device__ __forceinline__ float dpp_xor1(float x) {
  return __int_as_float(
      __builtin_amdgcn_update_dpp(0, __float_as_int(x), 0xB1, 0xF, 0xF, true));
}

// Butterfly W <- K W: bits 0..4 in-lane (packed), bit 5 across the lane pair.
__device__ __forceinline__ void butterfly_lane(v2f W[NPL], v2f A2) {
  // bit 0: partner is the other half of the same pair -> op_sel-swapped src1.
  // D.lo = a*W.hi + W.lo ; D.hi = a*W.lo + W.hi
#pragma unroll
  for (int k = 0; k < NPL; ++k) {
    v2f d;
    asm("v_pk_fma_f32 %0, %1, %2, %3 op_sel:[0,1,0] op_sel_hi:[1,0,1]"
        : "=v"(d) : "v"(A2), "v"(W[k]), "v"(W[k]));
    W[k] = d;
  }
  // bits 1..4: partner pair j = k ^ (1<<(b-1)); halves stay aligned.
#pragma unroll
  for (int b = 1; b < NBITS - 1; ++b) {
    const int m = 1 << (b - 1);
#pragma unroll
    for (int k = 0; k < NPL; ++k) {
      if ((k & m) == 0) {
        const int j = k | m;
        const v2f t0 = W[k], t1 = W[j];
        v2f d0, d1;
        asm("v_pk_fma_f32 %0, %1, %2, %3" : "=v"(d0) : "v"(A2), "v"(t1), "v"(t0));
        asm("v_pk_fma_f32 %0, %1, %2, %3" : "=v"(d1) : "v"(A2), "v"(t0), "v"(t1));
        W[k] = d0;
        W[j] = d1;
      }
    }
  }
  // bit 5: partner lane holds the same local index of the other state half.
#pragma unroll
  for (int k = 0; k < NPL; ++k) {
    const float px = dpp_xor1(W[k].x);
    const float py = dpp_xor1(W[k].y);
    W[k].x = fmaf(A2.x, px, W[k].x);
    W[k].y = fmaf(A2.y, py, W[k].y);
  }
}

// W <- X / W elementwise, one rcp per PAIR, fully packed.
__device__ __forceinline__ void div_step(v2f W[NPL], const v2f X[NPL]) {
#pragma unroll
  for (int k = 0; k < NPL; ++k) {
    v2f rv;
    rv.x = rcp(W[k].x * W[k].y);   // r in low half; high half never read
    v2f c, d;
    // c = {X.lo * W.hi, X.hi * W.lo}
    asm("v_pk_mul_f32 %0, %1, %2 op_sel:[0,1] op_sel_hi:[1,0]"
        : "=v"(c) : "v"(X[k]), "v"(W[k]));
    // W' = c * {r, r}  (src1 low half broadcast to both lanes)
    asm("v_pk_mul_f32 %0, %1, %2 op_sel:[0,0] op_sel_hi:[1,0]"
        : "=v"(d) : "v"(c), "v"(rv));
    W[k] = d;
  }
}

__global__ __launch_bounds__(256, 4) void emd_sinkhorn_kernel(
    const float* __restrict__ gp, const float* __restrict__ gq,
    float* __restrict__ out, int nbatch) {
  const int t = blockIdx.x * 256 + threadIdx.x;   // 2 threads per batch elem
  if (t >= 2 * nbatch) return;
  // thread t: batch = t>>1, state half h = t&1, states s = 32h + j.
  // gp[batch*64 + 32h + j] == gp[t*32 + j] -> contiguous per-thread blocks.

  const float4* __restrict__ p4 =
      reinterpret_cast<const float4*>(gp) + (size_t)t * (NL / 4);
  const float4* __restrict__ q4 =
      reinterpret_cast<const float4*>(gq) + (size_t)t * (NL / 4);

  v2f P[NPL], Q[NPL], W[NPL];

  // Load p,q ONCE, repack into register pairs.
#pragma unroll
  for (int k = 0; k < NL / 4; ++k) {
    const float4 tp = p4[k];
    P[2 * k + 0] = v2f{tp.x, tp.y};
    P[2 * k + 1] = v2f{tp.z, tp.w};
    const float4 tq = q4[k];
    Q[2 * k + 0] = v2f{tq.x, tq.y};
    Q[2 * k + 1] = v2f{tq.z, tq.w};
  }

  // Scale q by sum(p)/sum(q) (full 64-state sums: own half + partner half).
  // Both lanes of a pair compute bitwise-identical sums (a+b == b+a), so the
  // two Q halves are scaled consistently.
  float sp0 = 0.f, sq0 = 0.f;
#pragma unroll
  for (int k = 0; k < NPL; ++k) {
    sp0 += P[k].x + P[k].y;
    sq0 += Q[k].x + Q[k].y;
  }
  sp0 += dpp_xor1(sp0);
  sq0 += dpp_xor1(sq0);
  const float qscale = sp0 * rcp(sq0);
#pragma unroll
  for (int k = 0; k < NPL; ++k) {
    Q[k].x *= qscale;
    Q[k].y *= qscale;
  }

  // Pin p,q in registers: values become opaque -> no global-load remat.
#pragma unroll
  for (int k = 0; k < NPL; ++k) {
    asm volatile("" : "+v"(P[k]));
    asm volatile("" : "+v"(Q[k]));
  }

  v2f A2 = v2f{A, A};
  asm volatile("" : "+v"(A2));  // keep resident (VOP3P cannot take literals)

  // u0 = ones => K u0 propto ones => v1 propto q (scale drops out).
#pragma unroll
  for (int k = 0; k < NPL; ++k) W[k] = Q[k];

  // 49 full iterations: u = p/(K v); v' = q/(K u)  (up to global scalars).
#pragma unroll 1
  for (int it = 0; it < ITERS - 1; ++it) {
    butterfly_lane(W, A2);
    div_step(W, P);
    butterfly_lane(W, A2);
    div_step(W, Q);
  }

  // w = K v_50 ; u_50 = p/w formed on the fly in the readout.
  butterfly_lane(W, A2);

  const float sp = sp0;  // sum(p): same expression as v1's epilogue recompute
  float sx = 0.f;        // sum_i u_i * sum_b w[i^b]
#pragma unroll
  for (int k = 0; k < NPL; ++k) {
#pragma unroll
    for (int h = 0; h < 2; ++h) {
      const float pi = h ? P[k].y : P[k].x;
      const float wj = h ? W[k].y : W[k].x;
      const float ui = pi * rcp(wj);
      const int j = 2 * k + h;
      // neighbor sum, ascending bit order: j^1, j^2, j^4, j^8, j^16, j^32
      float nb = h ? W[k].x : W[k].y;  // j^1: other half of same pair
#pragma unroll
      for (int bb = 1; bb < NBITS - 1; ++bb) {
        const int jn = j ^ (1 << bb);
        nb += (jn & 1) ? W[jn >> 1].y : W[jn >> 1].x;
      }
      nb += dpp_xor1(wj);              // j^32: partner lane, same local index
      sx = fmaf(ui, nb, sx);
    }
  }
  sx += dpp_xor1(sx);                  // combine the two state halves

  if ((t & 1) == 0)
    out[t >> 1] = fmaf(sx * rcp(sp), EMD_SCALE, -EMD_DIAG);
}

}  // namespace

extern "C" void kernel_launch(void* const* d_in, const int* in_sizes, int n_in,
                              void* d_out, int out_size, void* d_ws, size_t ws_size,
                              hipStream_t stream) {
  const float* p = (const float*)d_in[0];
  const float* q = (const float*)d_in[1];
  // d_in[2] is the Hamming cost matrix; its tensor-product structure is
  // hardcoded (a = exp(-1/eps) = exp(-10)).
  float* out = (float*)d_out;

  const int nbatch = in_sizes[0] / 64;  // 262144
  const int nthreads = 2 * nbatch;      // one lane PAIR per batch element
  const int block = 256;
  const int grid = (nthreads + block - 1) / block;
  emd_sinkhorn_kernel<<<grid, block, 0, stream>>>(p, q, out, nbatch);
}

// Round 2
// 389.752 us; speedup vs baseline: 1.0898x; 1.0898x over previous
//
#include <hip/hip_runtime.h>

// EMD via Sinkhorn on 64 Hamming states, eps=0.1.
// K = exp(-C/eps) = tensor product of six 2x2 [[1,a],[a,1]], a = exp(-10)
//   => K-apply is 6 butterfly stages as PACKED fp32.
// NOTE (R1 post-mortem): v_pk_fma_f32 is HALF-RATE on gfx950 (4cy/wave64,
// FLOP-neutral vs scalar); packing buys instruction count, not FLOPs. The
// lane-pair/DPP split (R1) raised occupancy 20->37% but added issue slots
// (bit-5 via DPP = 4x the instructions of the in-lane pk stage) and
// regressed 332->360 us. This 1-lane/batch form is instruction-minimal:
//   512 pk + 64 mul + 64 rcp per iter = 2688 cy/iter/batch-wave
//   x50 iters x4 wave-rounds/SIMD = 537.6k cy = 224 us @2.4 GHz nominal;
//   at the m07-measured dense-VALU sustain (65.5% of nominal) = 342 us
//   ~= measured 332-338 us kernel time. This is the VALU-issue roofline.
// Scale invariance (map is 1-homogeneous): iterate on raw p and q scaled by
// sum(p)/sum(q); the single surviving 1/sum(p) is applied in the epilogue.
// Divide steps: batched-inverse pair trick (one rcp per 2 states; quad
// version rejected: u,v contrast reaches ~1/a^6 ~ 1e26, 4-products would
// overflow fp32) -- fully packed:
//   c  = v_pk_mul(X, W.swapped)        ; {X.lo*wh, X.hi*wl}
//   W' = v_pk_mul(c, r broadcast-low)  ; r = rcp(wl*wh) lives in the LOW
//        half of a v2f; op_sel_hi:[..,0] never reads the undef high half.
// EMD readout (w = K v_final, u = p/w):
//   emd = (a * sum_b u.X_b w) / ((1-a^2) * sum(p)) - 6a^2/(1-a^2)

namespace {

typedef float v2f __attribute__((ext_vector_type(2)));

constexpr int   N     = 64;
constexpr int   NP    = 32;   // register pairs; pair k = states {2k, 2k+1}
constexpr int   NBITS = 6;
constexpr int   ITERS = 50;

constexpr double Ad = 4.5399929762484854e-05;           // exp(-10)
constexpr float  A  = (float)Ad;
constexpr float  EMD_SCALE = (float)(Ad / (1.0 - Ad * Ad));
constexpr float  EMD_DIAG  = (float)(6.0 * Ad * Ad / (1.0 - Ad * Ad));

__device__ __forceinline__ float rcp(float x) { return __builtin_amdgcn_rcpf(x); }

// Packed butterfly: W <- K W across 32 register pairs.
__device__ __forceinline__ void butterfly_pk(v2f W[NP], v2f A2) {
  // bit 0: partner is the other half of the same pair -> op_sel-swapped src1.
  // D.lo = a*W.hi + W.lo ; D.hi = a*W.lo + W.hi
#pragma unroll
  for (int k = 0; k < NP; ++k) {
    v2f d;
    asm("v_pk_fma_f32 %0, %1, %2, %3 op_sel:[0,1,0] op_sel_hi:[1,0,1]"
        : "=v"(d) : "v"(A2), "v"(W[k]), "v"(W[k]));
    W[k] = d;
  }
  // bits 1..5: partner pair j = k ^ (1<<(b-1)); halves stay aligned.
#pragma unroll
  for (int b = 1; b < NBITS; ++b) {
    const int m = 1 << (b - 1);
#pragma unroll
    for (int k = 0; k < NP; ++k) {
      if ((k & m) == 0) {
        const int j = k | m;
        const v2f t0 = W[k], t1 = W[j];
        v2f d0, d1;
        asm("v_pk_fma_f32 %0, %1, %2, %3" : "=v"(d0) : "v"(A2), "v"(t1), "v"(t0));
        asm("v_pk_fma_f32 %0, %1, %2, %3" : "=v"(d1) : "v"(A2), "v"(t0), "v"(t1));
        W[k] = d0;
        W[j] = d1;
      }
    }
  }
}

// W <- X / W elementwise, one rcp per PAIR, fully packed.
__device__ __forceinline__ void div_step(v2f W[NP], const v2f X[NP]) {
#pragma unroll
  for (int k = 0; k < NP; ++k) {
    v2f rv;
    rv.x = rcp(W[k].x * W[k].y);   // r in low half; high half never read
    v2f c, d;
    // c = {X.lo * W.hi, X.hi * W.lo}
    asm("v_pk_mul_f32 %0, %1, %2 op_sel:[0,1] op_sel_hi:[1,0]"
        : "=v"(c) : "v"(X[k]), "v"(W[k]));
    // W' = c * {r, r}  (src1 low half broadcast to both lanes)
    asm("v_pk_mul_f32 %0, %1, %2 op_sel:[0,0] op_sel_hi:[1,0]"
        : "=v"(d) : "v"(c), "v"(rv));
    W[k] = d;
  }
}

__global__ __launch_bounds__(256, 2) void emd_sinkhorn_kernel(
    const float* __restrict__ gp, const float* __restrict__ gq,
    float* __restrict__ out, int nbatch) {
  const int b = blockIdx.x * 256 + threadIdx.x;
  if (b >= nbatch) return;

  const float4* __restrict__ p4 =
      reinterpret_cast<const float4*>(gp) + (size_t)b * (N / 4);
  const float4* __restrict__ q4 =
      reinterpret_cast<const float4*>(gq) + (size_t)b * (N / 4);

  v2f P[NP], Q[NP], W[NP];

  // Load p,q ONCE, repack into register pairs.
#pragma unroll
  for (int k = 0; k < N / 4; ++k) {
    const float4 tp = p4[k];
    P[2 * k + 0] = v2f{tp.x, tp.y};
    P[2 * k + 1] = v2f{tp.z, tp.w};
    const float4 tq = q4[k];
    Q[2 * k + 0] = v2f{tq.x, tq.y};
    Q[2 * k + 1] = v2f{tq.z, tq.w};
  }

  // Scale q by sum(p)/sum(q): output-invariant (1-homogeneous map), kills
  // the (sum_p/sum_q)^50 magnitude drift of the unnormalized iteration.
  float sp0 = 0.f, sq0 = 0.f;
#pragma unroll
  for (int k = 0; k < NP; ++k) {
    sp0 += P[k].x + P[k].y;
    sq0 += Q[k].x + Q[k].y;
  }
  const float qscale = sp0 * rcp(sq0);
#pragma unroll
  for (int k = 0; k < NP; ++k) {
    Q[k].x *= qscale;
    Q[k].y *= qscale;
  }

  // Pin p,q in registers: values become opaque -> no global-load remat.
#pragma unroll
  for (int k = 0; k < NP; ++k) {
    asm volatile("" : "+v"(P[k]));
    asm volatile("" : "+v"(Q[k]));
  }

  v2f A2 = v2f{A, A};
  asm volatile("" : "+v"(A2));  // keep resident (VOP3P cannot take literals)

  // u0 = ones => K u0 propto ones => v1 propto q (scale drops out).
#pragma unroll
  for (int k = 0; k < NP; ++k) W[k] = Q[k];

  // 49 full iterations: u = p/(K v); v' = q/(K u)  (up to global scalars).
#pragma unroll 1
  for (int it = 0; it < ITERS - 1; ++it) {
    butterfly_pk(W, A2);
    div_step(W, P);
    butterfly_pk(W, A2);
    div_step(W, Q);
  }

  // w = K v_50 ; u_50 = p/w formed on the fly in the readout.
  butterfly_pk(W, A2);

  float ws[N];
#pragma unroll
  for (int k = 0; k < NP; ++k) {
    ws[2 * k + 0] = W[k].x;
    ws[2 * k + 1] = W[k].y;
  }

  float sp = 0.f;  // sum(p) -- the only surviving normalization factor
  float sx = 0.f;  // sum_i u_i * sum_b w[i^b]
#pragma unroll
  for (int k = 0; k < NP; ++k) {
#pragma unroll
    for (int h = 0; h < 2; ++h) {
      const int i = 2 * k + h;
      const float pi = h ? P[k].y : P[k].x;
      sp += pi;
      const float ui = pi * rcp(ws[i]);
      float nb = ws[i ^ 1];
#pragma unroll
      for (int bb = 1; bb < NBITS; ++bb) nb += ws[i ^ (1 << bb)];
      sx = fmaf(ui, nb, sx);
    }
  }

  out[b] = fmaf(sx * rcp(sp), EMD_SCALE, -EMD_DIAG);
}

}  // namespace

extern "C" void kernel_launch(void* const* d_in, const int* in_sizes, int n_in,
                              void* d_out, int out_size, void* d_ws, size_t ws_size,
                              hipStream_t stream) {
  const float* p = (const float*)d_in[0];
  const float* q = (const float*)d_in[1];
  // d_in[2] is the Hamming cost matrix; its tensor-product structure is
  // hardcoded (a = exp(-1/eps) = exp(-10)).
  float* out = (float*)d_out;

  const int nbatch = in_sizes[0] / N;  // 262144
  const int block = 256;
  const int grid = (nbatch + block - 1) / block;
  emd_sinkhorn_kernel<<<grid, block, 0, stream>>>(p, q, out, nbatch);
}